// Round 4
// baseline (3860.904 us; speedup 1.0000x reference)
//
#include <hip/hip_runtime.h>
#include <math.h>
#include <stdint.h>

#define BATCH 4096
#define LATENT 256
#define H 512
#define A 64
#define SEQL 128
#define KCAT 576          // 64 (x) + 512 (h)
#define NSTEP 127
#define SEGLEN 16         // steps per persistent segment
#define NSEG 8            // 7*16 + 15 = 127

// persistent GRU kernel geometry
#define MB 256            // rows per m-group (16 m-groups)
#define JB 32             // j cols per block (16 j-blocks)
#define BST 584           // Bs row stride in elems (16B aligned)
#define AS_ELEMS (3 * 256 * 32)          // triple-buffered A tile, row-major [256][32]
#define BS_ELEMS (96 * BST)              // resident Wcat j-slice
#define GRU_LDS ((AS_ELEMS + BS_ELEMS) * 2)   // 161280 bytes <= 160 KiB

typedef __bf16 bf16x8 __attribute__((ext_vector_type(8)));
typedef float f32x4 __attribute__((ext_vector_type(4)));

__device__ __forceinline__ uint16_t f2bf(float f) {
    union { float f; uint32_t u; } v; v.f = f;
    uint32_t u = v.u + 0x7FFFu + ((v.u >> 16) & 1u);
    return (uint16_t)(u >> 16);
}

__device__ __forceinline__ float fast_sig(float x) {
    return __fdividef(1.0f, 1.0f + __expf(-x));
}
__device__ __forceinline__ float fast_tanh(float x) {
    return __fdividef(2.0f, 1.0f + __expf(-2.0f * x)) - 1.0f;
}

__device__ __forceinline__ f32x4 mfma16(bf16x8 a, bf16x8 b, f32x4 c) {
    return __builtin_amdgcn_mfma_f32_16x16x32_bf16(a, b, c, 0, 0, 0);
}

__device__ __forceinline__ void load_lds16(const void* g, void* l) {
    __builtin_amdgcn_global_load_lds(
        (const __attribute__((address_space(1))) uint32_t*)g,
        (__attribute__((address_space(3))) uint32_t*)l, 16, 0, 0);
}

// ---------------- prep kernels ----------------

__global__ __launch_bounds__(256) void cvt_bf16_kernel(const float* __restrict__ src,
                                                       uint16_t* __restrict__ dst, int n) {
    int idx = (blockIdx.x * 256 + threadIdx.x) * 4;
    if (idx < n) {
        float4 v = *(const float4*)(src + idx);
        dst[idx + 0] = f2bf(v.x); dst[idx + 1] = f2bf(v.y);
        dst[idx + 2] = f2bf(v.z); dst[idx + 3] = f2bf(v.w);
    }
}

// Wcat[n][0:64] = W_ih[n][:], Wcat[n][64:576] = W_hh[n][:]   (n in [0,1536))
__global__ __launch_bounds__(256) void wcat_kernel(const float* __restrict__ W_ih,
                                                   const float* __restrict__ W_hh,
                                                   uint16_t* __restrict__ Wcat) {
    int idx = blockIdx.x * 256 + threadIdx.x;
    if (idx < 1536 * KCAT) {
        int row = idx / KCAT, col = idx - row * KCAT;
        float v = (col < 64) ? W_ih[row * 64 + col] : W_hh[row * 512 + col - 64];
        Wcat[idx] = f2bf(v);
    }
}

__global__ __launch_bounds__(256) void bias_kernel(const float* __restrict__ b_ih,
                                                   const float* __restrict__ b_hh,
                                                   float* __restrict__ biases) {
    int idx = blockIdx.x * 256 + threadIdx.x;
    if (idx < 2048) {
        int seg = idx >> 9, j = idx & 511;
        float v;
        if (seg == 0) v = b_ih[j] + b_hh[j];
        else if (seg == 1) v = b_ih[512 + j] + b_hh[512 + j];
        else if (seg == 2) v = b_ih[1024 + j];
        else v = b_hh[1024 + j];
        biases[idx] = v;
    }
}

// per-segment X window, K-TILED: X2[sl][half][4096][32], half = a>>5
__global__ __launch_bounds__(256) void xseg_kernel(const float* __restrict__ target,
                                                   uint16_t* __restrict__ X,
                                                   int t0, int ns) {
    int idx = blockIdx.x * 256 + threadIdx.x;
    int e = idx * 4;                 // ns*BATCH*A elems, grid exact
    int a = e & 63;
    int b = (e >> 6) & (BATCH - 1);
    int sl = e >> 18;
    int t = t0 + sl;
    ushort4 o;
    if (t == 0) {
        o.x = f2bf((a == 0) ? 16.0f : -16.0f);
        uint16_t m16 = f2bf(-16.0f);
        o.y = m16; o.z = m16; o.w = m16;
    } else {
        float4 v = *(const float4*)(target + ((size_t)b * SEQL + t) * A + a);
        o.x = f2bf(v.x); o.y = f2bf(v.y); o.z = f2bf(v.z); o.w = f2bf(v.w);
    }
    size_t d = ((size_t)(sl * 2 + (a >> 5)) * BATCH + b) * 32 + (a & 31);
    *(ushort4*)(X + d) = o;
}

__global__ __launch_bounds__(256) void bosout_kernel(float* __restrict__ out) {
    int idx = blockIdx.x * 256 + threadIdx.x;  // BATCH*A
    int a = idx & (A - 1);
    int b = idx >> 6;
    out[(size_t)b * SEQL * A + a] = (a == 0) ? 16.0f : -16.0f;
}

// ---------------- generic bf16 MFMA GEMM ----------------
// C[M,N] = act(A[M,K] @ W[N,K]^T + bias[N]); BM=128, BN=128, BK=32, 256 thr.
// tiledA: A stored as [sl(=m>>12)*16 + k/32][4096][32]  (hall2 layout)
// tiledOutB: outb stored as [n>>5][BATCH][32]           (tiled h layout)
__global__ __launch_bounds__(256)
void gemm_kernel(const uint16_t* __restrict__ Abf, int lda,
                 const uint16_t* __restrict__ Wbf,
                 const float* __restrict__ bias,
                 uint16_t* __restrict__ outb, float* __restrict__ outf,
                 int ldc, int K, int do_tanh, int tiledA, int tiledOutB)
{
    __shared__ __align__(16) uint16_t As[128 * 32];
    __shared__ __align__(16) uint16_t Bs[128 * 32];

    const int tid = threadIdx.x;
    const int w = tid >> 6, l = tid & 63;
    const int quad = l >> 4, lan = l & 15;
    const int m0 = blockIdx.y * 128;
    const int n0 = blockIdx.x * 128;
    const int wm = (w >> 1) * 64;
    const int wn = (w & 1) * 64;

    f32x4 acc[4][4];
#pragma unroll
    for (int i = 0; i < 4; ++i)
#pragma unroll
        for (int j = 0; j < 4; ++j) acc[i][j] = (f32x4){0.f, 0.f, 0.f, 0.f};

    const int arow = (l >> 2);
    const int kc8 = (l & 3) * 8;

    for (int k0 = 0; k0 < K; k0 += 32) {
        __syncthreads();
#pragma unroll
        for (int i = 0; i < 2; ++i) {
            int row = i * 64 + w * 16 + arow;
            int m = m0 + row;
            const uint16_t* src = tiledA
                ? Abf + ((size_t)((m >> 12) * 16 + (k0 >> 5)) * BATCH + (m & (BATCH - 1))) * 32 + kc8
                : Abf + (size_t)m * lda + k0 + kc8;
            load_lds16(src, As + i * 2048 + w * 512 + l * 8);
        }
#pragma unroll
        for (int i = 0; i < 2; ++i) {
            int row = i * 64 + w * 16 + arow;
            load_lds16(Wbf + (size_t)(n0 + row) * K + k0 + kc8,
                       Bs + i * 2048 + w * 512 + l * 8);
        }
        __syncthreads();

        bf16x8 af[4], bf[4];
#pragma unroll
        for (int mi = 0; mi < 4; ++mi)
            af[mi] = *(const bf16x8*)(As + (wm + mi * 16 + lan) * 32 + quad * 8);
#pragma unroll
        for (int nj = 0; nj < 4; ++nj)
            bf[nj] = *(const bf16x8*)(Bs + (wn + nj * 16 + lan) * 32 + quad * 8);
#pragma unroll
        for (int mi = 0; mi < 4; ++mi)
#pragma unroll
            for (int nj = 0; nj < 4; ++nj)
                acc[mi][nj] = mfma16(af[mi], bf[nj], acc[mi][nj]);
    }

#pragma unroll
    for (int mi = 0; mi < 4; ++mi) {
#pragma unroll
        for (int nj = 0; nj < 4; ++nj) {
#pragma unroll
            for (int reg = 0; reg < 4; ++reg) {
                int m = m0 + wm + mi * 16 + quad * 4 + reg;
                int n = n0 + wn + nj * 16 + lan;
                float v = acc[mi][nj][reg] + bias[n];
                if (do_tanh) v = fast_tanh(v);
                if (outf) outf[(size_t)m * ldc + n] = v;
                if (outb) {
                    size_t d = tiledOutB
                        ? ((size_t)(n >> 5) * BATCH + m) * 32 + (n & 31)
                        : (size_t)m * ldc + n;
                    outb[d] = f2bf(v);
                }
            }
        }
    }
}

// ---------------- persistent segmented GRU, pipelined, tiled I/O ----------------
// 256 blocks x 512 thr, 1 block/CU. 16 m-groups x 16 j-blocks. Wcat j-slice
// LDS-resident; fp32 h carry in registers. h exchanged via hall2 in K-TILE-MAJOR
// layout [s][kt][4096][32]: producer block (mg,jb) writes its 16KB slice
// contiguously; consumer tile reads are base + g*16B (perfectly coalesced).
// K-loop: 3-buffer A ring, prefetch distance 2, counted s_waitcnt vmcnt(4).
__global__ __launch_bounds__(512)
void gru_seg_kernel(const uint16_t* __restrict__ Xseg,   // [ns][2][4096][32] tiled
                    const uint16_t* __restrict__ Wcat,
                    const float* __restrict__ biases,
                    const uint16_t* __restrict__ hprevT,  // [16][4096][32] tiled h_{t0-1}
                    float* __restrict__ hA,               // fp32 carry (in/out), row-major
                    uint16_t* __restrict__ hall2,         // [SEGLEN][16][4096][32]
                    uint32_t* __restrict__ cnt,           // [16][SEGLEN], zeroed
                    int nsteps)
{
    extern __shared__ __align__(16) uint16_t lds[];
    uint16_t* As = lds;                  // [3][256][32] row-major
    uint16_t* Bs = lds + AS_ELEMS;       // [96][BST]

    const int tid = threadIdx.x;
    const int bid = blockIdx.x;
    const int xcd = bid & 7;
    const int kk  = bid >> 3;
    const int jb  = kk & 15;
    const int mg  = xcd + ((kk >> 4) << 3);
    const int j0  = jb * JB;
    const int mbase = mg * MB;

    const int w = tid >> 6, l = tid & 63;
    const int quad = l >> 4, lan = l & 15;
    const int wm = (w >> 1) * 64;        // 4 m-strips of 64
    const int wj = (w & 1) * 16;         // 2 j-halves of 16
    const int jcol = j0 + wj + lan;

    // ---- fp32 h carry + biases: load and DRAIN before the vmcnt ledger ----
    float hreg[4][4];
#pragma unroll
    for (int mi = 0; mi < 4; ++mi)
#pragma unroll
        for (int r = 0; r < 4; ++r)
            hreg[mi][r] = hA[(size_t)(mbase + wm + mi * 16 + quad * 4 + r) * H + jcol];
    const float br = biases[jcol], bz = biases[512 + jcol];
    const float bi = biases[1024 + jcol], bh = biases[1536 + jcol];
    __builtin_amdgcn_sched_barrier(0);
    asm volatile("s_waitcnt vmcnt(0)");
    __builtin_amdgcn_sched_barrier(0);

    // ---- stage resident Wcat j-slice (plain loads; retired via ds_writes) ----
    for (int i = tid; i < 96 * 72; i += 512) {
        int row = i / 72, c = i - row * 72;
        int wrow = ((row >> 5) << 9) + j0 + (row & 31);
        uint4 v = *(const uint4*)(Wcat + (size_t)wrow * KCAT + c * 8);
        *(uint4*)(Bs + row * BST + c * 8) = v;
    }
    __builtin_amdgcn_sched_barrier(0);

    // tile (s2, kt2) -> global_load_lds into buffer bsel; all sources tiled:
    // source addr = tilebase + g*16B, dest = As[bsel] + g*16B  (coalesced)
    auto stage = [&](int s2, int kt2, int bsel) {
        const uint16_t* tb;
        if (kt2 < 2)       tb = Xseg   + ((size_t)(s2 * 2 + kt2) * BATCH + mbase) * 32;
        else if (s2 == 0)  tb = hprevT + ((size_t)(kt2 - 2) * BATCH + mbase) * 32;
        else               tb = hall2  + ((size_t)((s2 - 1) * 16 + (kt2 - 2)) * BATCH + mbase) * 32;
#pragma unroll
        for (int i = 0; i < 2; ++i) {
            int g = i * 512 + tid;
            load_lds16(tb + (size_t)g * 8, As + bsel * 8192 + g * 8);
        }
    };

    // prologue: tiles 0,1 (x of step 0)
    stage(0, 0, 0);
    stage(0, 1, 1);
    __builtin_amdgcn_sched_barrier(0);
    asm volatile("s_waitcnt lgkmcnt(0)");   // Bs ds_writes done
    __builtin_amdgcn_s_barrier();
    __builtin_amdgcn_sched_barrier(0);

    f32x4 acc[4][4];  // [mi][r, z, in, hn]
#pragma unroll
    for (int i = 0; i < 4; ++i)
#pragma unroll
        for (int j = 0; j < 4; ++j) acc[i][j] = (f32x4){0.f, 0.f, 0.f, 0.f};

    const int N = 18 * nsteps;
    int bufc = 0;                         // ts % 3

    for (int s = 0; s < nsteps; ++s) {
        for (int kt = 0; kt < 18; ++kt) {
            const int ts = s * 18 + kt;
            // flag wait before first h tile of step s is staged (at kt==0)
            if (kt == 0 && s > 0) {
                if (tid == 0) {
                    const uint32_t* fl = cnt + mg * SEGLEN + (s - 1);
                    while (__hip_atomic_load(fl, __ATOMIC_RELAXED,
                                             __HIP_MEMORY_SCOPE_AGENT) < 16u)
                        __builtin_amdgcn_s_sleep(8);
                }
                __builtin_amdgcn_s_barrier();
                __builtin_amdgcn_sched_barrier(0);
            }
            // prefetch tile ts+2
            if (ts + 2 < N) {
                int kt2 = kt + 2, s2 = s;
                if (kt2 >= 18) { kt2 -= 18; ++s2; }
                int sb = bufc + 2; if (sb >= 3) sb -= 3;
                stage(s2, kt2, sb);
            }
            __builtin_amdgcn_sched_barrier(0);
            if (ts + 2 < N)      asm volatile("s_waitcnt vmcnt(4)");
            else if (ts + 1 < N) asm volatile("s_waitcnt vmcnt(2)");
            else                 asm volatile("s_waitcnt vmcnt(0)");
            __builtin_amdgcn_sched_barrier(0);
            __builtin_amdgcn_s_barrier();       // tile ts ready in all waves
            __builtin_amdgcn_sched_barrier(0);

            bf16x8 af[4], bfr[3];
#pragma unroll
            for (int mi = 0; mi < 4; ++mi)
                af[mi] = *(const bf16x8*)(As + bufc * 8192 +
                                          (wm + mi * 16 + lan) * 32 + quad * 8);
#pragma unroll
            for (int g = 0; g < 3; ++g)
                bfr[g] = *(const bf16x8*)(Bs + (g * 32 + wj + lan) * BST + kt * 32 + quad * 8);

#pragma unroll
            for (int mi = 0; mi < 4; ++mi) {
                acc[mi][0] = mfma16(af[mi], bfr[0], acc[mi][0]);
                acc[mi][1] = mfma16(af[mi], bfr[1], acc[mi][1]);
            }
            if (kt < 2) {
#pragma unroll
                for (int mi = 0; mi < 4; ++mi)
                    acc[mi][2] = mfma16(af[mi], bfr[2], acc[mi][2]);
            } else {
#pragma unroll
                for (int mi = 0; mi < 4; ++mi)
                    acc[mi][3] = mfma16(af[mi], bfr[2], acc[mi][3]);
            }
            __builtin_amdgcn_sched_barrier(0);
            __builtin_amdgcn_s_barrier();       // protect buffer before overwrite
            __builtin_amdgcn_sched_barrier(0);
            ++bufc; if (bufc >= 3) bufc = 0;
        }

        // epilogue: gates + fp32 carry in regs; publish CONTIGUOUS 16KB tile
        uint16_t* ht = hall2 + ((size_t)(s * 16 + jb) * BATCH + mbase) * 32;
#pragma unroll
        for (int mi = 0; mi < 4; ++mi) {
#pragma unroll
            for (int r = 0; r < 4; ++r) {
                float R  = acc[mi][0][r] + br;
                float Z  = acc[mi][1][r] + bz;
                float I  = acc[mi][2][r] + bi;
                float HN = acc[mi][3][r] + bh;
                float rg = fast_sig(R);
                float zg = fast_sig(Z);
                float nn = fast_tanh(I + rg * HN);
                float hv = (1.0f - zg) * nn + zg * hreg[mi][r];
                hreg[mi][r] = hv;
                ht[(size_t)(wm + mi * 16 + quad * 4 + r) * 32 + wj + lan] = f2bf(hv);
                acc[mi][0][r] = 0.f; acc[mi][1][r] = 0.f;
                acc[mi][2][r] = 0.f; acc[mi][3][r] = 0.f;
            }
        }
        __syncthreads();  // drains vmcnt in ALL waves: h stores complete (once/step)
        if (tid == 0) {
            (void)__hip_atomic_fetch_add(cnt + mg * SEGLEN + s, 1u,
                                         __ATOMIC_RELEASE, __HIP_MEMORY_SCOPE_AGENT);
        }
    }

    // write fp32 carry back for next segment
#pragma unroll
    for (int mi = 0; mi < 4; ++mi)
#pragma unroll
        for (int r = 0; r < 4; ++r)
            hA[(size_t)(mbase + wm + mi * 16 + quad * 4 + r) * H + jcol] = hreg[mi][r];
}

// ---------------- fused decoder d2+d3 ----------------
__global__ __launch_bounds__(256)
void d23_kernel(const uint16_t* __restrict__ p1,   // [M][512]
                const uint16_t* __restrict__ Wm2,  // [64][512]
                const float* __restrict__ bm2,
                const uint16_t* __restrict__ Wm3,  // [64][64]
                const float* __restrict__ bm3,
                float* __restrict__ out, int t0)
{
    __shared__ __align__(16) uint16_t As[128 * 32];
    __shared__ __align__(16) uint16_t B2[64 * 32];
    __shared__ __align__(16) uint16_t W3[64 * 64];
    __shared__ __align__(16) uint16_t Ps[128 * 80];

    const int tid = threadIdx.x;
    const int w = tid >> 6, l = tid & 63;
    const int quad = l >> 4, lan = l & 15;
    const int m0 = blockIdx.y * 128;
    const int wm = w * 32;

#pragma unroll
    for (int i = 0; i < 2; ++i) {
        int g = i * 256 + tid;
        int row = g >> 3, kc = (g & 7) * 8;
        load_lds16(Wm3 + (size_t)row * 64 + kc, W3 + (size_t)g * 8);
    }

    f32x4 acc[2][4];
#pragma unroll
    for (int i = 0; i < 2; ++i)
#pragma unroll
        for (int j = 0; j < 4; ++j) acc[i][j] = (f32x4){0.f, 0.f, 0.f, 0.f};

    for (int k0 = 0; k0 < 512; k0 += 32) {
        __syncthreads();
#pragma unroll
        for (int i = 0; i < 2; ++i) {
            int g = i * 256 + tid;
            int row = g >> 2, kc = (g & 3) * 8;
            load_lds16(p1 + (size_t)(m0 + row) * 512 + k0 + kc, As + (size_t)g * 8);
        }
        {
            int g = tid;
            int row = g >> 2, kc = (g & 3) * 8;
            load_lds16(Wm2 + (size_t)row * 512 + k0 + kc, B2 + (size_t)g * 8);
        }
        __syncthreads();

        bf16x8 af[2], bf[4];
#pragma unroll
        for (int mi = 0; mi < 2; ++mi)
            af[mi] = *(const bf16x8*)(As + (wm + mi * 16 + lan) * 32 + quad * 8);
#pragma unroll
        for (int nj = 0; nj < 4; ++nj)
            bf[nj] = *(const bf16x8*)(B2 + (nj * 16 + lan) * 32 + quad * 8);
#pragma unroll
        for (int mi = 0; mi < 2; ++mi)
#pragma unroll
            for (int nj = 0; nj < 4; ++nj)
                acc[mi][nj] = mfma16(af[mi], bf[nj], acc[mi][nj]);
    }

#pragma unroll
    for (int mi = 0; mi < 2; ++mi)
#pragma unroll
        for (int nj = 0; nj < 4; ++nj)
#pragma unroll
            for (int reg = 0; reg < 4; ++reg) {
                int row = wm + mi * 16 + quad * 4 + reg;
                int n = nj * 16 + lan;
                float v = fast_tanh(acc[mi][nj][reg] + bm2[n]);
                Ps[row * 80 + n] = f2bf(v);
            }
    __syncthreads();

    f32x4 a3[2][4];
#pragma unroll
    for (int i = 0; i < 2; ++i)
#pragma unroll
        for (int j = 0; j < 4; ++j) a3[i][j] = (f32x4){0.f, 0.f, 0.f, 0.f};

#pragma unroll
    for (int ks = 0; ks < 64; ks += 32) {
        bf16x8 af[2], bf[4];
#pragma unroll
        for (int mi = 0; mi < 2; ++mi)
            af[mi] = *(const bf16x8*)(Ps + (wm + mi * 16 + lan) * 80 + ks + quad * 8);
#pragma unroll
        for (int nj = 0; nj < 4; ++nj)
            bf[nj] = *(const bf16x8*)(W3 + (nj * 16 + lan) * 64 + ks + quad * 8);
#pragma unroll
        for (int mi = 0; mi < 2; ++mi)
#pragma unroll
            for (int nj = 0; nj < 4; ++nj)
                a3[mi][nj] = mfma16(af[mi], bf[nj], a3[mi][nj]);
    }

#pragma unroll
    for (int mi = 0; mi < 2; ++mi)
#pragma unroll
        for (int nj = 0; nj < 4; ++nj)
#pragma unroll
            for (int reg = 0; reg < 4; ++reg) {
                int m = m0 + wm + mi * 16 + quad * 4 + reg;
                int n = nj * 16 + lan;
                int b = m & (BATCH - 1), tl = m >> 12;
                out[(size_t)b * SEQL * A + (size_t)(t0 + tl + 1) * A + n] =
                    a3[mi][nj][reg] + bm3[n];
            }
}

// ---------------- host ----------------

extern "C" void kernel_launch(void* const* d_in, const int* in_sizes, int n_in,
                              void* d_out, int out_size, void* d_ws, size_t ws_size,
                              hipStream_t stream)
{
    const float* latent = (const float*)d_in[0];
    const float* target = (const float*)d_in[1];
    const float* Wd1 = (const float*)d_in[2];
    const float* bd1 = (const float*)d_in[3];
    const float* Wd2 = (const float*)d_in[4];
    const float* bd2 = (const float*)d_in[5];
    const float* Wd3 = (const float*)d_in[6];
    const float* bd3 = (const float*)d_in[7];
    const float* W_ih = (const float*)d_in[8];
    const float* W_hh = (const float*)d_in[9];
    const float* b_ih = (const float*)d_in[10];
    const float* b_hh = (const float*)d_in[11];
    const float* Wm1 = (const float*)d_in[12];
    const float* bm1 = (const float*)d_in[13];
    const float* Wm2 = (const float*)d_in[14];
    const float* bm2 = (const float*)d_in[15];
    const float* Wm3 = (const float*)d_in[16];
    const float* bm3 = (const float*)d_in[17];

    float* out = (float*)d_out;
    uint8_t* ws = (uint8_t*)d_ws;

    size_t off = 0;
    auto carve = [&](size_t bytes) { void* p = ws + off; off += (bytes + 255) & ~(size_t)255; return p; };
    uint16_t* latb = (uint16_t*)carve((size_t)BATCH * LATENT * 2);
    uint16_t* wd1b = (uint16_t*)carve((size_t)H * LATENT * 2);
    uint16_t* wd2b = (uint16_t*)carve((size_t)H * H * 2);
    uint16_t* wd3b = (uint16_t*)carve((size_t)H * H * 2);
    uint16_t* wm1b = (uint16_t*)carve((size_t)H * H * 2);
    uint16_t* wm2b = (uint16_t*)carve((size_t)A * H * 2);
    uint16_t* wm3b = (uint16_t*)carve((size_t)A * A * 2);
    uint16_t* wcat = (uint16_t*)carve((size_t)1536 * KCAT * 2);
    float* biases  = (float*)carve(2048 * 4);
    uint16_t* t1b  = (uint16_t*)carve((size_t)BATCH * H * 2);
    uint16_t* t2b  = (uint16_t*)carve((size_t)BATCH * H * 2);
    uint16_t* h0t  = (uint16_t*)carve((size_t)BATCH * H * 2);   // tiled h0 [16][4096][32]
    float* hA      = (float*)carve((size_t)BATCH * H * 4);
    uint16_t* Xseg = (uint16_t*)carve((size_t)SEGLEN * BATCH * A * 2);   // 8.4 MB tiled
    uint16_t* hall2= (uint16_t*)carve((size_t)SEGLEN * 16 * BATCH * 32 * 2);  // 67 MB tiled
    uint16_t* p1   = (uint16_t*)carve((size_t)8 * BATCH * H * 2);        // 33.5 MB
    uint32_t* cnt  = (uint32_t*)carve((size_t)16 * SEGLEN * 4);

    static int attr_done = 0;
    if (!attr_done) {
        hipFuncSetAttribute((const void*)gru_seg_kernel,
                            hipFuncAttributeMaxDynamicSharedMemorySize, GRU_LDS);
        attr_done = 1;
    }

    dim3 blk(256);

    // ---- prep ----
    auto cvt = [&](const float* s, uint16_t* d, int n) {
        cvt_bf16_kernel<<<dim3((n / 4 + 255) / 256), blk, 0, stream>>>(s, d, n);
    };
    cvt(latent, latb, BATCH * LATENT);
    cvt(Wd1, wd1b, H * LATENT);
    cvt(Wd2, wd2b, H * H);
    cvt(Wd3, wd3b, H * H);
    cvt(Wm1, wm1b, H * H);
    cvt(Wm2, wm2b, A * H);
    cvt(Wm3, wm3b, A * A);
    wcat_kernel<<<dim3((1536 * KCAT + 255) / 256), blk, 0, stream>>>(W_ih, W_hh, wcat);
    bias_kernel<<<dim3(8), blk, 0, stream>>>(b_ih, b_hh, biases);
    bosout_kernel<<<dim3(BATCH * A / 256), blk, 0, stream>>>(out);

    // ---- initial MLP (latent -> h0); last GEMM emits TILED bf16 h0 ----
    gemm_kernel<<<dim3(H / 128, BATCH / 128), blk, 0, stream>>>(
        latb, LATENT, wd1b, bd1, t1b, nullptr, H, LATENT, 1, 0, 0);
    gemm_kernel<<<dim3(H / 128, BATCH / 128), blk, 0, stream>>>(
        t1b, H, wd2b, bd2, t2b, nullptr, H, H, 1, 0, 0);
    gemm_kernel<<<dim3(H / 128, BATCH / 128), blk, 0, stream>>>(
        t2b, H, wd3b, bd3, h0t, hA, H, H, 0, 0, 1);

    // ---- persistent GRU segments + batched decoder ----
    for (int seg = 0; seg < NSEG; ++seg) {
        const int t0 = seg * SEGLEN;
        const int ns = (seg == NSEG - 1) ? (NSTEP - t0) : SEGLEN;  // 15 last
        xseg_kernel<<<dim3(ns * 256), blk, 0, stream>>>(target, Xseg, t0, ns);
        hipMemsetAsync(cnt, 0, (size_t)16 * SEGLEN * 4, stream);
        const uint16_t* hp0 = (seg == 0)
            ? h0t : hall2 + (size_t)(SEGLEN - 1) * 16 * BATCH * 32;
        gru_seg_kernel<<<dim3(256), dim3(512), GRU_LDS, stream>>>(
            Xseg, wcat, biases, hp0, hA, hall2, cnt, ns);
        // decoder in half-windows of <=8 steps (bounds p1 at 33.5 MB)
        int done = 0;
        while (done < ns) {
            const int hw = (ns - done >= 8) ? 8 : (ns - done);
            const int M = hw * BATCH;
            gemm_kernel<<<dim3(H / 128, M / 128), blk, 0, stream>>>(
                hall2 + (size_t)done * 16 * BATCH * 32, H, wm1b, bm1,
                p1, nullptr, H, H, 1, 1, 0);
            d23_kernel<<<dim3(1, M / 128), blk, 0, stream>>>(
                p1, wm2b, bm2, wm3b, bm3, out, t0 + done);
            done += hw;
        }
    }
}

// Round 6
// 3355.187 us; speedup vs baseline: 1.1507x; 1.1507x over previous
//
#include <hip/hip_runtime.h>
#include <math.h>
#include <stdint.h>

#define BATCH 4096
#define LATENT 256
#define H 512
#define A 64
#define SEQL 128
#define KCAT 576          // 64 (x) + 512 (h)
#define NSTEP 127
#define SEGLEN 16         // steps per persistent segment
#define NSEG 8            // 7*16 + 15 = 127

// persistent GRU kernel geometry
#define MB 256            // rows per m-group (16 m-groups)
#define JB 32             // j cols per block (16 j-blocks)
#define BST 584           // Bs row stride in elems (16B aligned, 2-way alias = free)
#define AS_ELEMS (3 * 256 * 32)          // triple-buffered A tile [256][32] (chunk-swizzled)
#define BS_ELEMS (96 * BST)              // resident Wcat j-slice
#define GRU_LDS ((AS_ELEMS + BS_ELEMS) * 2)   // 161280 bytes <= 160 KiB

// tile arena: tile(s2,kt2,mg) elem offset = s2*STEP_E + kt2*TS_E + mg*TILE_E
#define TILE_E 8192                       // 256 rows x 32 cols
#define TS_E   (16 * TILE_E)              // 131072
#define STEP_E (18 * TS_E)                // 2359296
#define HALL_E ((size_t)SEGLEN * STEP_E)  // 37,748,736 elems = 75.5 MB
#define STASH_E ((size_t)16 * 16 * TILE_E) // 4 MB: [kc][mg] tiles

typedef __bf16 bf16x8 __attribute__((ext_vector_type(8)));
typedef float f32x4 __attribute__((ext_vector_type(4)));

__device__ __forceinline__ uint16_t f2bf(float f) {
    union { float f; uint32_t u; } v; v.f = f;
    uint32_t u = v.u + 0x7FFFu + ((v.u >> 16) & 1u);
    return (uint16_t)(u >> 16);
}

__device__ __forceinline__ float fast_sig(float x) {
    return __fdividef(1.0f, 1.0f + __expf(-x));
}
__device__ __forceinline__ float fast_tanh(float x) {
    return __fdividef(2.0f, 1.0f + __expf(-2.0f * x)) - 1.0f;
}

__device__ __forceinline__ f32x4 mfma16(bf16x8 a, bf16x8 b, f32x4 c) {
    return __builtin_amdgcn_mfma_f32_16x16x32_bf16(a, b, c, 0, 0, 0);
}

__device__ __forceinline__ void load_lds16(const void* g, void* l) {
    __builtin_amdgcn_global_load_lds(
        (const __attribute__((address_space(1))) uint32_t*)g,
        (__attribute__((address_space(3))) uint32_t*)l, 16, 0, 0);
}

// chunk swizzle within a tile row: c' = c ^ (row&3) ^ ((row>>2)&3)
__device__ __forceinline__ int cswz(int c, int row) {
    return c ^ (row & 3) ^ ((row >> 2) & 3);
}

// ---------------- prep kernels ----------------

__global__ __launch_bounds__(256) void cvt_bf16_kernel(const float* __restrict__ src,
                                                       uint16_t* __restrict__ dst, int n) {
    int idx = (blockIdx.x * 256 + threadIdx.x) * 4;
    if (idx < n) {
        float4 v = *(const float4*)(src + idx);
        dst[idx + 0] = f2bf(v.x); dst[idx + 1] = f2bf(v.y);
        dst[idx + 2] = f2bf(v.z); dst[idx + 3] = f2bf(v.w);
    }
}

__global__ __launch_bounds__(256) void wcat_kernel(const float* __restrict__ W_ih,
                                                   const float* __restrict__ W_hh,
                                                   uint16_t* __restrict__ Wcat) {
    int idx = blockIdx.x * 256 + threadIdx.x;
    if (idx < 1536 * KCAT) {
        int row = idx / KCAT, col = idx - row * KCAT;
        float v = (col < 64) ? W_ih[row * 64 + col] : W_hh[row * 512 + col - 64];
        Wcat[idx] = f2bf(v);
    }
}

__global__ __launch_bounds__(256) void bias_kernel(const float* __restrict__ b_ih,
                                                   const float* __restrict__ b_hh,
                                                   float* __restrict__ biases) {
    int idx = blockIdx.x * 256 + threadIdx.x;
    if (idx < 2048) {
        int seg = idx >> 9, j = idx & 511;
        float v;
        if (seg == 0) v = b_ih[j] + b_hh[j];
        else if (seg == 1) v = b_ih[512 + j] + b_hh[512 + j];
        else if (seg == 2) v = b_ih[1024 + j];
        else v = b_hh[1024 + j];
        biases[idx] = v;
    }
}

// x tiles into arena slots [sl][0..1], swizzled chunk layout
__global__ __launch_bounds__(256) void xseg_kernel(const float* __restrict__ target,
                                                   uint16_t* __restrict__ hall,
                                                   int t0, int ns) {
    int idx = blockIdx.x * 256 + threadIdx.x;
    int e = idx * 4;                 // ns*BATCH*A elems, grid exact
    int a = e & 63;
    int b = (e >> 6) & (BATCH - 1);
    int sl = e >> 18;
    int t = t0 + sl;
    ushort4 o;
    if (t == 0) {
        o.x = f2bf((a == 0) ? 16.0f : -16.0f);
        uint16_t m16 = f2bf(-16.0f);
        o.y = m16; o.z = m16; o.w = m16;
    } else {
        float4 v = *(const float4*)(target + ((size_t)b * SEQL + t) * A + a);
        o.x = f2bf(v.x); o.y = f2bf(v.y); o.z = f2bf(v.z); o.w = f2bf(v.w);
    }
    int rw = b & 255;
    size_t d = (size_t)sl * STEP_E + (size_t)(a >> 5) * TS_E + (size_t)(b >> 8) * TILE_E
             + (size_t)rw * 32 + cswz((a & 31) >> 3, rw) * 8 + (a & 7);
    *(ushort4*)(hall + d) = o;
}

__global__ __launch_bounds__(256) void bosout_kernel(float* __restrict__ out) {
    int idx = blockIdx.x * 256 + threadIdx.x;  // BATCH*A
    int a = idx & (A - 1);
    int b = idx >> 6;
    out[(size_t)b * SEQL * A + a] = (a == 0) ? 16.0f : -16.0f;
}

// ---------------- generic bf16 MFMA GEMM ----------------
// C[M,N] = act(A[M,K] @ W[N,K]^T + bias[N]); BM=128, BN=128, BK=32, 256 thr.
// tiledA: read from arena slots (done+sl -> slot done+sl+1, or stash at stash_sl)
// tiledOutB: write outb in stash tile layout (swizzled chunks)
__global__ __launch_bounds__(256)
void gemm_kernel(const uint16_t* __restrict__ Abf, int lda,
                 const uint16_t* __restrict__ Wbf,
                 const float* __restrict__ bias,
                 uint16_t* __restrict__ outb, float* __restrict__ outf,
                 int ldc, int K, int do_tanh, int tiledA, int tiledOutB,
                 const uint16_t* __restrict__ hall, const uint16_t* __restrict__ stashA,
                 int done, int stash_sl)
{
    __shared__ __align__(16) uint16_t As[128 * 32];
    __shared__ __align__(16) uint16_t Bs[128 * 32];

    const int tid = threadIdx.x;
    const int w = tid >> 6, l = tid & 63;
    const int quad = l >> 4, lan = l & 15;
    const int m0 = blockIdx.y * 128;
    const int n0 = blockIdx.x * 128;
    const int wm = (w >> 1) * 64;
    const int wn = (w & 1) * 64;

    f32x4 acc[4][4];
#pragma unroll
    for (int i = 0; i < 4; ++i)
#pragma unroll
        for (int j = 0; j < 4; ++j) acc[i][j] = (f32x4){0.f, 0.f, 0.f, 0.f};

    const int arow = (l >> 2);
    const int kc8 = (l & 3) * 8;

    for (int k0 = 0; k0 < K; k0 += 32) {
        __syncthreads();
        const uint16_t* abase = nullptr;
        if (tiledA) {
            int sstep = done + (m0 >> 12);
            int kc = k0 >> 5;
            int mg = (m0 >> 8) & 15;
            abase = (sstep == stash_sl)
                ? stashA + ((size_t)kc * 16 + mg) * TILE_E
                : hall + (size_t)(sstep + 1) * STEP_E + (size_t)(2 + kc) * TS_E
                       + (size_t)mg * TILE_E;
        }
#pragma unroll
        for (int i = 0; i < 2; ++i) {
            int row = i * 64 + w * 16 + arow;
            const uint16_t* src;
            if (tiledA) {
                int rowt = (m0 & 255) + row;
                src = abase + (size_t)rowt * 32 + cswz(l & 3, rowt) * 8;
            } else {
                src = Abf + (size_t)(m0 + row) * lda + k0 + kc8;
            }
            load_lds16(src, As + i * 2048 + w * 512 + l * 8);
        }
#pragma unroll
        for (int i = 0; i < 2; ++i) {
            int row = i * 64 + w * 16 + arow;
            load_lds16(Wbf + (size_t)(n0 + row) * K + k0 + kc8,
                       Bs + i * 2048 + w * 512 + l * 8);
        }
        __syncthreads();

        bf16x8 af[4], bf[4];
#pragma unroll
        for (int mi = 0; mi < 4; ++mi)
            af[mi] = *(const bf16x8*)(As + (wm + mi * 16 + lan) * 32 + quad * 8);
#pragma unroll
        for (int nj = 0; nj < 4; ++nj)
            bf[nj] = *(const bf16x8*)(Bs + (wn + nj * 16 + lan) * 32 + quad * 8);
#pragma unroll
        for (int mi = 0; mi < 4; ++mi)
#pragma unroll
            for (int nj = 0; nj < 4; ++nj)
                acc[mi][nj] = mfma16(af[mi], bf[nj], acc[mi][nj]);
    }

#pragma unroll
    for (int mi = 0; mi < 4; ++mi) {
#pragma unroll
        for (int nj = 0; nj < 4; ++nj) {
#pragma unroll
            for (int reg = 0; reg < 4; ++reg) {
                int m = m0 + wm + mi * 16 + quad * 4 + reg;
                int n = n0 + wn + nj * 16 + lan;
                float v = acc[mi][nj][reg] + bias[n];
                if (do_tanh) v = fast_tanh(v);
                if (outf) outf[(size_t)m * ldc + n] = v;
                if (outb) {
                    size_t d;
                    if (tiledOutB) {
                        int rw = m & 255;
                        d = ((size_t)(n >> 5) * 16 + (m >> 8)) * TILE_E
                          + (size_t)rw * 32 + cswz((n & 31) >> 3, rw) * 8 + (n & 7);
                    } else {
                        d = (size_t)m * ldc + n;
                    }
                    outb[d] = f2bf(v);
                }
            }
        }
    }
}

// ---------------- persistent segmented GRU, pipelined, linear arena ----------------
// 256 blocks x 512 thr, 1 block/CU. 16 m-groups x 16 j-blocks. Wcat j-slice
// LDS-resident; fp32 h carry in registers. All staging sources live in one
// linear arena (x slots written by xseg; h slots written by producer peers at
// slot s+1; step-0 h from stash). Fully unrolled 18-iter K loop: ring index,
// buffer selects, Bs offsets, gate split all compile-time; staging address is
// base + compile-time offset. Counted vmcnt(4), 2 barriers/iter, setprio MFMA.
__global__ __launch_bounds__(512)
void gru_seg_kernel(uint16_t* hall,                      // arena (R/W)
                    uint16_t* stash,                     // init-h in, last-h out
                    const uint16_t* __restrict__ Wcat,
                    const float* __restrict__ biases,
                    float* __restrict__ hA,              // fp32 carry (in/out)
                    uint32_t* __restrict__ cnt,          // [16][SEGLEN] this segment, zeroed
                    int nsteps)
{
    extern __shared__ __align__(16) uint16_t lds[];
    uint16_t* As = lds;                  // [3][256][32]
    uint16_t* Bs = lds + AS_ELEMS;       // [96][BST]

    const int tid = threadIdx.x;
    const int bid = blockIdx.x;
    const int xcd = bid & 7;
    const int kk  = bid >> 3;
    const int jb  = kk & 15;
    const int mg  = xcd + ((kk >> 4) << 3);
    const int j0  = jb * JB;
    const int mbase = mg * MB;

    const int w = tid >> 6, l = tid & 63;
    const int quad = l >> 4, lan = l & 15;
    const int wm = (w >> 1) * 64;        // 4 m-strips of 64
    const int wj = (w & 1) * 16;         // 2 j-halves of 16
    const int jcol = j0 + wj + lan;
    const int xt = (lan & 3) ^ ((lan >> 2) & 3);   // af chunk swizzle term

    // ---- fp32 h carry + biases: load and DRAIN before the vmcnt ledger ----
    float hreg[4][4];
#pragma unroll
    for (int mi = 0; mi < 4; ++mi)
#pragma unroll
        for (int r = 0; r < 4; ++r)
            hreg[mi][r] = hA[(size_t)(mbase + wm + mi * 16 + quad * 4 + r) * H + jcol];
    const float br = biases[jcol], bz = biases[512 + jcol];
    const float bi = biases[1024 + jcol], bh = biases[1536 + jcol];
    __builtin_amdgcn_sched_barrier(0);
    asm volatile("s_waitcnt vmcnt(0)" ::: "memory");
    __builtin_amdgcn_sched_barrier(0);

    // ---- stage resident Wcat j-slice (VGPR loads + ds_writes) ----
    for (int i = tid; i < 96 * 72; i += 512) {
        int row = i / 72, c = i - row * 72;
        int wrow = ((row >> 5) << 9) + j0 + (row & 31);
        uint4 v = *(const uint4*)(Wcat + (size_t)wrow * KCAT + c * 8);
        *(uint4*)(Bs + row * BST + c * 8) = v;
    }
    __builtin_amdgcn_sched_barrier(0);

    // per-thread constant staging offsets
    const size_t toff = (size_t)mg * TILE_E + (size_t)tid * 8;

    // prologue: x tiles (0,0) and (0,1)
    {
        const uint16_t* x0 = hall + toff;
        load_lds16(x0,               As + tid * 8);
        load_lds16(x0 + 4096,        As + 4096 + tid * 8);
        load_lds16(x0 + TS_E,        As + TILE_E + tid * 8);
        load_lds16(x0 + TS_E + 4096, As + TILE_E + 4096 + tid * 8);
    }
    __builtin_amdgcn_sched_barrier(0);
    asm volatile("s_waitcnt lgkmcnt(0)" ::: "memory");   // Bs ds_writes done
    __builtin_amdgcn_s_barrier();
    __builtin_amdgcn_sched_barrier(0);

    f32x4 acc[4][4];  // [mi][r, z, in, hn]
#pragma unroll
    for (int i = 0; i < 4; ++i)
#pragma unroll
        for (int j = 0; j < 4; ++j) acc[i][j] = (f32x4){0.f, 0.f, 0.f, 0.f};

    for (int s = 0; s < nsteps; ++s) {
        // base for h tiles of this step (kt2 in 2..17): hb + kt2*TS_E
        const uint16_t* hb = (s == 0)
            ? (stash + toff) - 2 * TS_E
            : hall + (size_t)s * STEP_E + toff;
        // base for next step's x tiles (kt2 = 0,1 of s+1); dummy = current x
        const int snx = (s + 1 < nsteps) ? (s + 1) : s;
        const uint16_t* xn = hall + (size_t)snx * STEP_E + toff;

#pragma unroll
        for (int kt = 0; kt < 18; ++kt) {
            if (kt == 0 && s > 0) {
                if (tid == 0) {
                    const uint32_t* fl = cnt + mg * SEGLEN + (s - 1);
                    while (__hip_atomic_load(fl, __ATOMIC_RELAXED,
                                             __HIP_MEMORY_SCOPE_AGENT) < 16u)
                        __builtin_amdgcn_s_sleep(2);
                    __builtin_amdgcn_fence(__ATOMIC_ACQUIRE, "agent");
                }
                __builtin_amdgcn_s_barrier();
            }
            // stage tile ts+2 into ring buffer (kt+2)%3
            {
                const int sb = (kt + 2) % 3;
                const uint16_t* src = (kt < 16) ? hb + (size_t)(kt + 2) * TS_E
                                                : xn + (size_t)(kt - 16) * TS_E;
                load_lds16(src,        As + sb * TILE_E + tid * 8);
                load_lds16(src + 4096, As + sb * TILE_E + 4096 + tid * 8);
            }
            asm volatile("s_waitcnt vmcnt(4)" ::: "memory");
            __builtin_amdgcn_s_barrier();
            __builtin_amdgcn_sched_barrier(0);

            const uint16_t* Ab = As + (kt % 3) * TILE_E;
            bf16x8 af[4], bfr[3];
#pragma unroll
            for (int mi = 0; mi < 4; ++mi) {
                int row = wm + mi * 16 + lan;
                af[mi] = *(const bf16x8*)(Ab + row * 32 + ((quad ^ xt) * 8));
            }
#pragma unroll
            for (int g = 0; g < 3; ++g)
                bfr[g] = *(const bf16x8*)(Bs + (g * 32 + wj + lan) * BST + kt * 32 + quad * 8);

            __builtin_amdgcn_s_setprio(1);
#pragma unroll
            for (int mi = 0; mi < 4; ++mi) {
                acc[mi][0] = mfma16(af[mi], bfr[0], acc[mi][0]);
                acc[mi][1] = mfma16(af[mi], bfr[1], acc[mi][1]);
            }
            if (kt < 2) {
#pragma unroll
                for (int mi = 0; mi < 4; ++mi)
                    acc[mi][2] = mfma16(af[mi], bfr[2], acc[mi][2]);
            } else {
#pragma unroll
                for (int mi = 0; mi < 4; ++mi)
                    acc[mi][3] = mfma16(af[mi], bfr[2], acc[mi][3]);
            }
            __builtin_amdgcn_s_setprio(0);
            __builtin_amdgcn_sched_barrier(0);
            __builtin_amdgcn_s_barrier();
            __builtin_amdgcn_sched_barrier(0);
        }

        // epilogue: gates + fp32 carry in regs; publish swizzled tile at slot s+1
        uint16_t* wt = (s == 15)
            ? stash + ((size_t)jb * 16 + mg) * TILE_E
            : hall + (size_t)(s + 1) * STEP_E + (size_t)(2 + jb) * TS_E
                   + (size_t)mg * TILE_E;
#pragma unroll
        for (int mi = 0; mi < 4; ++mi) {
#pragma unroll
            for (int r = 0; r < 4; ++r) {
                float R  = acc[mi][0][r] + br;
                float Z  = acc[mi][1][r] + bz;
                float I  = acc[mi][2][r] + bi;
                float HN = acc[mi][3][r] + bh;
                float rg = fast_sig(R);
                float zg = fast_sig(Z);
                float nn = fast_tanh(I + rg * HN);
                float hv = (1.0f - zg) * nn + zg * hreg[mi][r];
                hreg[mi][r] = hv;
                int row = wm + mi * 16 + quad * 4 + r;
                int col = wj + lan;
                wt[(size_t)row * 32 + cswz(col >> 3, row) * 8 + (col & 7)] = f2bf(hv);
                acc[mi][0][r] = 0.f; acc[mi][1][r] = 0.f;
                acc[mi][2][r] = 0.f; acc[mi][3][r] = 0.f;
            }
        }
        __syncthreads();  // drains vmcnt in ALL waves: h stores complete
        if (tid == 0) {
            (void)__hip_atomic_fetch_add(cnt + mg * SEGLEN + s, 1u,
                                         __ATOMIC_RELEASE, __HIP_MEMORY_SCOPE_AGENT);
        }
    }

    // write fp32 carry back for next segment
#pragma unroll
    for (int mi = 0; mi < 4; ++mi)
#pragma unroll
        for (int r = 0; r < 4; ++r)
            hA[(size_t)(mbase + wm + mi * 16 + quad * 4 + r) * H + jcol] = hreg[mi][r];
}

// ---------------- fused decoder d2+d3 ----------------
__global__ __launch_bounds__(256)
void d23_kernel(const uint16_t* __restrict__ p1,   // [M][512]
                const uint16_t* __restrict__ Wm2,  // [64][512]
                const float* __restrict__ bm2,
                const uint16_t* __restrict__ Wm3,  // [64][64]
                const float* __restrict__ bm3,
                float* __restrict__ out, int t0)
{
    __shared__ __align__(16) uint16_t As[128 * 32];
    __shared__ __align__(16) uint16_t B2[64 * 32];
    __shared__ __align__(16) uint16_t W3[64 * 64];
    __shared__ __align__(16) uint16_t Ps[128 * 80];

    const int tid = threadIdx.x;
    const int w = tid >> 6, l = tid & 63;
    const int quad = l >> 4, lan = l & 15;
    const int m0 = blockIdx.y * 128;
    const int wm = w * 32;

#pragma unroll
    for (int i = 0; i < 2; ++i) {
        int g = i * 256 + tid;
        int row = g >> 3, kc = (g & 7) * 8;
        load_lds16(Wm3 + (size_t)row * 64 + kc, W3 + (size_t)g * 8);
    }

    f32x4 acc[2][4];
#pragma unroll
    for (int i = 0; i < 2; ++i)
#pragma unroll
        for (int j = 0; j < 4; ++j) acc[i][j] = (f32x4){0.f, 0.f, 0.f, 0.f};

    for (int k0 = 0; k0 < 512; k0 += 32) {
        __syncthreads();
#pragma unroll
        for (int i = 0; i < 2; ++i) {
            int g = i * 256 + tid;
            int row = g >> 2, kc = (g & 3) * 8;
            load_lds16(p1 + (size_t)(m0 + row) * 512 + k0 + kc, As + (size_t)g * 8);
        }
        {
            int g = tid;
            int row = g >> 2, kc = (g & 3) * 8;
            load_lds16(Wm2 + (size_t)row * 512 + k0 + kc, B2 + (size_t)g * 8);
        }
        __syncthreads();

        bf16x8 af[2], bf[4];
#pragma unroll
        for (int mi = 0; mi < 2; ++mi)
            af[mi] = *(const bf16x8*)(As + (wm + mi * 16 + lan) * 32 + quad * 8);
#pragma unroll
        for (int nj = 0; nj < 4; ++nj)
            bf[nj] = *(const bf16x8*)(B2 + (nj * 16 + lan) * 32 + quad * 8);
#pragma unroll
        for (int mi = 0; mi < 2; ++mi)
#pragma unroll
            for (int nj = 0; nj < 4; ++nj)
                acc[mi][nj] = mfma16(af[mi], bf[nj], acc[mi][nj]);
    }

#pragma unroll
    for (int mi = 0; mi < 2; ++mi)
#pragma unroll
        for (int nj = 0; nj < 4; ++nj)
#pragma unroll
            for (int reg = 0; reg < 4; ++reg) {
                int row = wm + mi * 16 + quad * 4 + reg;
                int n = nj * 16 + lan;
                float v = fast_tanh(acc[mi][nj][reg] + bm2[n]);
                Ps[row * 80 + n] = f2bf(v);
            }
    __syncthreads();

    f32x4 a3[2][4];
#pragma unroll
    for (int i = 0; i < 2; ++i)
#pragma unroll
        for (int j = 0; j < 4; ++j) a3[i][j] = (f32x4){0.f, 0.f, 0.f, 0.f};

#pragma unroll
    for (int ks = 0; ks < 64; ks += 32) {
        bf16x8 af[2], bf[4];
#pragma unroll
        for (int mi = 0; mi < 2; ++mi)
            af[mi] = *(const bf16x8*)(Ps + (wm + mi * 16 + lan) * 80 + ks + quad * 8);
#pragma unroll
        for (int nj = 0; nj < 4; ++nj)
            bf[nj] = *(const bf16x8*)(W3 + (nj * 16 + lan) * 64 + ks + quad * 8);
#pragma unroll
        for (int mi = 0; mi < 2; ++mi)
#pragma unroll
            for (int nj = 0; nj < 4; ++nj)
                a3[mi][nj] = mfma16(af[mi], bf[nj], a3[mi][nj]);
    }

#pragma unroll
    for (int mi = 0; mi < 2; ++mi)
#pragma unroll
        for (int nj = 0; nj < 4; ++nj)
#pragma unroll
            for (int reg = 0; reg < 4; ++reg) {
                int m = m0 + wm + mi * 16 + quad * 4 + reg;
                int n = nj * 16 + lan;
                int b = m & (BATCH - 1), tl = m >> 12;
                out[(size_t)b * SEQL * A + (size_t)(t0 + tl + 1) * A + n] =
                    a3[mi][nj][reg] + bm3[n];
            }
}

// ---------------- host ----------------

extern "C" void kernel_launch(void* const* d_in, const int* in_sizes, int n_in,
                              void* d_out, int out_size, void* d_ws, size_t ws_size,
                              hipStream_t stream)
{
    const float* latent = (const float*)d_in[0];
    const float* target = (const float*)d_in[1];
    const float* Wd1 = (const float*)d_in[2];
    const float* bd1 = (const float*)d_in[3];
    const float* Wd2 = (const float*)d_in[4];
    const float* bd2 = (const float*)d_in[5];
    const float* Wd3 = (const float*)d_in[6];
    const float* bd3 = (const float*)d_in[7];
    const float* W_ih = (const float*)d_in[8];
    const float* W_hh = (const float*)d_in[9];
    const float* b_ih = (const float*)d_in[10];
    const float* b_hh = (const float*)d_in[11];
    const float* Wm1 = (const float*)d_in[12];
    const float* bm1 = (const float*)d_in[13];
    const float* Wm2 = (const float*)d_in[14];
    const float* bm2 = (const float*)d_in[15];
    const float* Wm3 = (const float*)d_in[16];
    const float* bm3 = (const float*)d_in[17];

    float* out = (float*)d_out;
    uint8_t* ws = (uint8_t*)d_ws;

    size_t off = 0;
    auto carve = [&](size_t bytes) { void* p = ws + off; off += (bytes + 255) & ~(size_t)255; return p; };
    uint16_t* latb = (uint16_t*)carve((size_t)BATCH * LATENT * 2);
    uint16_t* wd1b = (uint16_t*)carve((size_t)H * LATENT * 2);
    uint16_t* wd2b = (uint16_t*)carve((size_t)H * H * 2);
    uint16_t* wd3b = (uint16_t*)carve((size_t)H * H * 2);
    uint16_t* wm1b = (uint16_t*)carve((size_t)H * H * 2);
    uint16_t* wm2b = (uint16_t*)carve((size_t)A * H * 2);
    uint16_t* wm3b = (uint16_t*)carve((size_t)A * A * 2);
    uint16_t* wcat = (uint16_t*)carve((size_t)1536 * KCAT * 2);
    float* biases  = (float*)carve(2048 * 4);
    uint16_t* t1b  = (uint16_t*)carve((size_t)BATCH * H * 2);
    uint16_t* t2b  = (uint16_t*)carve((size_t)BATCH * H * 2);
    float* hA      = (float*)carve((size_t)BATCH * H * 4);
    uint16_t* hall = (uint16_t*)carve(HALL_E * 2);            // 75.5 MB arena
    uint16_t* stash= (uint16_t*)carve(STASH_E * 2);           // 4 MB
    uint16_t* p1   = (uint16_t*)carve((size_t)8 * BATCH * H * 2);  // 33.5 MB
    uint32_t* cnt  = (uint32_t*)carve((size_t)NSEG * 16 * SEGLEN * 4);  // per-seg regions

    static int attr_done = 0;
    if (!attr_done) {
        hipFuncSetAttribute((const void*)gru_seg_kernel,
                            hipFuncAttributeMaxDynamicSharedMemorySize, GRU_LDS);
        attr_done = 1;
    }

    dim3 blk(256);

    // ---- prep ----
    auto cvt = [&](const float* s, uint16_t* d, int n) {
        cvt_bf16_kernel<<<dim3((n / 4 + 255) / 256), blk, 0, stream>>>(s, d, n);
    };
    cvt(latent, latb, BATCH * LATENT);
    cvt(Wd1, wd1b, H * LATENT);
    cvt(Wd2, wd2b, H * H);
    cvt(Wd3, wd3b, H * H);
    cvt(Wm1, wm1b, H * H);
    cvt(Wm2, wm2b, A * H);
    cvt(Wm3, wm3b, A * A);
    wcat_kernel<<<dim3((1536 * KCAT + 255) / 256), blk, 0, stream>>>(W_ih, W_hh, wcat);
    bias_kernel<<<dim3(8), blk, 0, stream>>>(b_ih, b_hh, biases);
    bosout_kernel<<<dim3(BATCH * A / 256), blk, 0, stream>>>(out);
    hipMemsetAsync(cnt, 0, (size_t)NSEG * 16 * SEGLEN * 4, stream);  // once

    // ---- initial MLP (latent -> h0); last GEMM emits h0 into STASH (tiled) ----
    gemm_kernel<<<dim3(H / 128, BATCH / 128), blk, 0, stream>>>(
        latb, LATENT, wd1b, bd1, t1b, nullptr, H, LATENT, 1, 0, 0,
        nullptr, nullptr, 0, 0);
    gemm_kernel<<<dim3(H / 128, BATCH / 128), blk, 0, stream>>>(
        t1b, H, wd2b, bd2, t2b, nullptr, H, H, 1, 0, 0,
        nullptr, nullptr, 0, 0);
    gemm_kernel<<<dim3(H / 128, BATCH / 128), blk, 0, stream>>>(
        t2b, H, wd3b, bd3, stash, hA, H, H, 0, 0, 1,
        nullptr, nullptr, 0, 0);

    // ---- persistent GRU segments + batched decoder ----
    for (int seg = 0; seg < NSEG; ++seg) {
        const int t0 = seg * SEGLEN;
        const int ns = (seg == NSEG - 1) ? (NSTEP - t0) : SEGLEN;  // 15 last
        const int stash_sl = (ns == 16) ? 15 : (1 << 30);
        xseg_kernel<<<dim3(ns * 256), blk, 0, stream>>>(target, hall, t0, ns);
        gru_seg_kernel<<<dim3(256), dim3(512), GRU_LDS, stream>>>(
            hall, stash, wcat, biases, hA, cnt + (size_t)seg * 16 * SEGLEN, ns);
        // decoder in half-windows of <=8 steps (bounds p1 at 33.5 MB)
        int done = 0;
        while (done < ns) {
            const int hw = (ns - done >= 8) ? 8 : (ns - done);
            const int M = hw * BATCH;
            gemm_kernel<<<dim3(H / 128, M / 128), blk, 0, stream>>>(
                nullptr, 0, wm1b, bm1, p1, nullptr, H, H, 1, 1, 0,
                hall, stash, done, stash_sl);
            d23_kernel<<<dim3(1, M / 128), blk, 0, stream>>>(
                p1, wm2b, bm2, wm3b, bm3, out, t0 + done);
            done += hw;
        }
    }
}